// Round 8
// baseline (34.686 us; speedup 1.0000x reference)
//
#include <hip/hip_runtime.h>

// GraphUpSamplingLayer: 3-D k=1 NN argmin + batched feature gather.
// B=4, C=512, M=2048 (coarse points), N=8192 (dense points), D=3.
constexpr int B = 4;
constexpr int C = 512;
constexpr int M = 2048;
constexpr int N = 8192;

// ---------------------------------------------------------------------------
// v6 argmin: wave-owns-4-queries, lane-owns-candidate-slice, zero arrays.
//
// Measured ladder (timed-mode, corrected R6 calibration): v1=28 (latency),
// v2=17 (LDS-issue: 1M uniform ds_read), v3=24.7 (failed scalarization),
// v4=30/v5=22 (lambda-ref float4 arrays -> scratch, rule #20). v6:
//  - Q=4 queries WAVE-uniform: one per-lane ds_read_b128 feeds 4 pairs
//    -> 262K total ds_reads (~5.1us LDS pipe, 1/4 of v2).
//  - 1024 blocks x 512 thr = 8 waves/SIMD (LDS 32KB x 4 blocks/CU = 128KB);
//    __launch_bounds__(512,8) pins VGPR <= 64 (est ~45, no spill).
//  - ALL hot state in named scalars; 1-deep named prefetch (c/cc).
// Per pair: 3 fma (score = h - p.s, h staged in float4.w; validated absmax
// 0.0 in R7) + cmp + 2 cndmask = 6 VALU. Model: ~2K cyc/wave x 8 waves/SIMD
// ~= 6.7us.
// Tie-break = jnp first-occurrence: in-lane scan m-ascending with strict <;
// cross-lane reduce lexicographic (d, m) on raw floats (works for negative
// scores; NOT bit-packed).
// ---------------------------------------------------------------------------
__global__ __launch_bounds__(512, 8) void nn_argmin_v6(
    const float* __restrict__ pos,      // [B][N][3]
    const float* __restrict__ sub_pos,  // [B][M][3]
    int* __restrict__ idx_out)          // [B][N]
{
    __shared__ float4 sp[M];            // 32 KB: (x, y, z, ||s||^2/2)

    const int b  = blockIdx.x >> 8;     // 256 blocks per batch
    const int n0 = (blockIdx.x & 255) << 5;  // 32 queries per block
    const int t  = threadIdx.x;
    const int w    = t >> 6;            // wave 0..7 (owns 4 queries)
    const int lane = t & 63;            // candidate slice within the wave

    const float* spb = sub_pos + (size_t)b * (M * 3);
    #pragma unroll
    for (int i = t; i < M; i += 512) {
        const float x = spb[i * 3 + 0];
        const float y = spb[i * 3 + 1];
        const float z = spb[i * 3 + 2];
        sp[i] = make_float4(x, y, z, 0.5f * fmaf(z, z, fmaf(y, y, x * x)));
    }
    __syncthreads();

    // 4 wave-uniform queries (same address in every lane -> scalarizable).
    const float* pp = pos + ((size_t)b * N + n0 + (w << 2)) * 3;
    const float px0 = pp[0],  py0 = pp[1],  pz0 = pp[2];
    const float px1 = pp[3],  py1 = pp[4],  pz1 = pp[5];
    const float px2 = pp[6],  py2 = pp[7],  pz2 = pp[8];
    const float px3 = pp[9],  py3 = pp[10], pz3 = pp[11];

    float b0 = 1e30f, b1 = 1e30f, b2 = 1e30f, b3 = 1e30f;
    int   m0 = 0,     m1 = 0,     m2 = 0,     m3 = 0;

    float4 c = sp[lane];                // prefetch iter 0
    #pragma unroll 4
    for (int i = 0; i < 32; ++i) {
        const float4 cc = c;
        c = sp[((((i + 1) & 31) << 6) + lane)];   // 1-deep prefetch (wraps, ok)
        const int m = (i << 6) + lane;
        float s;
        s = fmaf(-cc.x, px0, cc.w); s = fmaf(-cc.y, py0, s); s = fmaf(-cc.z, pz0, s);
        { const bool lt = s < b0; b0 = lt ? s : b0; m0 = lt ? m : m0; }
        s = fmaf(-cc.x, px1, cc.w); s = fmaf(-cc.y, py1, s); s = fmaf(-cc.z, pz1, s);
        { const bool lt = s < b1; b1 = lt ? s : b1; m1 = lt ? m : m1; }
        s = fmaf(-cc.x, px2, cc.w); s = fmaf(-cc.y, py2, s); s = fmaf(-cc.z, pz2, s);
        { const bool lt = s < b2; b2 = lt ? s : b2; m2 = lt ? m : m2; }
        s = fmaf(-cc.x, px3, cc.w); s = fmaf(-cc.y, py3, s); s = fmaf(-cc.z, pz3, s);
        { const bool lt = s < b3; b3 = lt ? s : b3; m3 = lt ? m : m3; }
    }

    // Full-wave lexicographic (d, m) argmin reduce == jnp first-occurrence.
    #pragma unroll
    for (int off = 1; off < 64; off <<= 1) {
        float ob; int om;
        ob = __shfl_xor(b0, off, 64); om = __shfl_xor(m0, off, 64);
        if (ob < b0 || (ob == b0 && om < m0)) { b0 = ob; m0 = om; }
        ob = __shfl_xor(b1, off, 64); om = __shfl_xor(m1, off, 64);
        if (ob < b1 || (ob == b1 && om < m1)) { b1 = ob; m1 = om; }
        ob = __shfl_xor(b2, off, 64); om = __shfl_xor(m2, off, 64);
        if (ob < b2 || (ob == b2 && om < m2)) { b2 = ob; m2 = om; }
        ob = __shfl_xor(b3, off, 64); om = __shfl_xor(m3, off, 64);
        if (ob < b3 || (ob == b3 && om < m3)) { b3 = ob; m3 = om; }
    }

    if (lane == 0) {
        int* o = idx_out + (size_t)b * N + n0 + (w << 2);
        o[0] = m0; o[1] = m1; o[2] = m2; o[3] = m3;
    }
}

// ---------------------------------------------------------------------------
// Phase 2: out[b][c][n] = sub_x[b][c][idx[b][n]]
// ~85% of the 64 MB-write roofline (sub_x rereads are L2/L3-absorbed).
// ---------------------------------------------------------------------------
__global__ __launch_bounds__(256) void gather_kernel(
    const float* __restrict__ sub_x,  // [B][C][M]
    const int* __restrict__ idx,      // [B][N]
    float* __restrict__ out)          // [B][C][N]
{
    __shared__ float row[M];          // 8 KB

    const int b = blockIdx.x >> 9;    // C = 512
    const int c = blockIdx.x & 511;
    const int t = threadIdx.x;

    const float* rsrc = sub_x + ((size_t)b * C + c) * M;
    for (int i = t; i < M; i += 256) row[i] = rsrc[i];
    __syncthreads();

    const int4* iv = (const int4*)(idx + (size_t)b * N);
    float4* ov = (float4*)(out + ((size_t)b * C + c) * N);
    #pragma unroll
    for (int i = t; i < N / 4; i += 256) {
        const int4 ii = iv[i];
        float4 v;
        v.x = row[ii.x];
        v.y = row[ii.y];
        v.z = row[ii.z];
        v.w = row[ii.w];
        ov[i] = v;
    }
}

extern "C" void kernel_launch(void* const* d_in, const int* in_sizes, int n_in,
                              void* d_out, int out_size, void* d_ws, size_t ws_size,
                              hipStream_t stream) {
    const float* sub_x   = (const float*)d_in[0];  // [B][C][M]
    const float* sub_pos = (const float*)d_in[1];  // [B][M][3]
    const float* pos     = (const float*)d_in[2];  // [B][N][3]
    float* out = (float*)d_out;                    // [B][C][N]
    int* idx = (int*)d_ws;                         // B*N*4 = 128 KB scratch

    nn_argmin_v6<<<B * (N / 32), 512, 0, stream>>>(pos, sub_pos, idx);
    gather_kernel<<<B * C, 256, 0, stream>>>(sub_x, idx, out);
}